// Round 6
// baseline (1724.271 us; speedup 1.0000x reference)
//
#include <hip/hip_runtime.h>
#include <math.h>

#define N_NODES 100000
#define N_EDGES 3200000
#define F_IN    512
#define HID     16
#define NCLS    7
#define ALPHA   0.1f
#define K_HOPS  10

// bucketing: 128 nodes per bucket
#define SHIFT   7
#define BWIDTH  128
#define NBUCK   782
#define CHUNK   2048
#define EPT     8                                   // CHUNK / 256
#define NCHUNK  ((N_EDGES + CHUNK - 1) / CHUNK)     // 1563

// persistent-kernel geometry: 1024 blocks x 256 thr = 4 blocks/CU on 256 CUs.
// LDS 18.4KB/block -> 74KB/CU (<160); 16 waves/CU; launch_bounds caps VGPR<=128.
#define NB      1024
#define BT      256
#define NWAVES  (NB * (BT / 64))                    // 4096

// ---- workspace layout (4-byte element offsets); no aliasing ----
#define OFF_BAR     0u          // int[16] grid-barrier counters
#define OFF_BCNT    1024u       // int[782]
#define OFF_BSTART  2048u       // int[783]
#define OFF_BCUR    3072u       // int[782]
#define OFF_RP      4096u       // int[100001]
#define OFF_DINV    104448u     // float[100000]
#define OFF_COL     204800u     // int[3200000]
#define OFF_BINNED  3404800u    // uint[3200000]
#define OFF_H0      6604800u    // float[100000*16]
#define OFF_H1      8204800u    // float[100000*16]
#define OFF_Z       9804800u    // float[100000*8]

#define XW_ROWS 64
#define XW_KT   32
#define XW_S    36
#define XW_NT   (F_IN / XW_KT)                      // 16
#define XW_TILES ((N_NODES + XW_ROWS - 1) / XW_ROWS) // 1563

// device-scope grid barrier: all NB blocks arrive, then proceed.
// release: __threadfence (wb own XCD L2) before arrive; acquire: fence after.
__device__ __forceinline__ void gsync(int* bar, int idx) {
    __syncthreads();
    if (threadIdx.x == 0) {
        __threadfence();
        atomicAdd(&bar[idx], 1);
        while (__hip_atomic_load(&bar[idx], __ATOMIC_RELAXED,
                                 __HIP_MEMORY_SCOPE_AGENT) < NB)
            __builtin_amdgcn_s_sleep(2);
    }
    __syncthreads();
    __threadfence();
}

__global__ void __launch_bounds__(BT, 4)
k_fused(const float* __restrict__ x, const int* __restrict__ src,
        const int* __restrict__ dst,
        const float* __restrict__ W1, const float* __restrict__ b1,
        const float* __restrict__ Wl, const float* __restrict__ bl,
        const float* __restrict__ W2, const float* __restrict__ b2,
        int* __restrict__ bar, int* __restrict__ bcnt,
        int* __restrict__ bstart, int* __restrict__ bcur,
        int* __restrict__ rp, float* __restrict__ dinv,
        int* __restrict__ col, unsigned int* __restrict__ binned,
        float* __restrict__ h0s, float* __restrict__ h1,
        float* __restrict__ zs, float* __restrict__ out) {
    __shared__ __align__(16) int smem[4608];   // 18432 B union
    int tid = threadIdx.x;

    // ---------------- P1: bucket histogram ----------------
    {
        int* h = smem;
        for (int i = tid; i < NBUCK; i += BT) h[i] = 0;
        __syncthreads();
        for (int e = blockIdx.x * BT + tid; e < N_EDGES; e += NB * BT)
            atomicAdd(&h[dst[e] >> SHIFT], 1);
        __syncthreads();
        for (int i = tid; i < NBUCK; i += BT) {
            int v = h[i];
            if (v) atomicAdd(&bcnt[i], v);
        }
    }
    gsync(bar, 0);

    // ---------------- P2: scan bucket counts (block 0) ----------------
    if (blockIdx.x == 0) {
        int* s0 = smem;
        int* s1 = smem + 1024;
        for (int j = tid; j < 1024; j += BT) s0[j] = (j < NBUCK) ? bcnt[j] : 0;
        __syncthreads();
        int cur = 0;
        for (int off = 1; off < 1024; off <<= 1) {
            int* a = cur ? s1 : s0;
            int* b = cur ? s0 : s1;
            for (int j = tid; j < 1024; j += BT)
                b[j] = a[j] + ((j >= off) ? a[j - off] : 0);
            __syncthreads();
            cur ^= 1;
        }
        int* a = cur ? s1 : s0;
        for (int j = tid; j < 1024; j += BT) {
            if (j < NBUCK) {
                int ex = a[j] - bcnt[j];     // exclusive
                bstart[j] = ex;
                bcur[j] = ex;
            }
        }
        if (tid == 0) bstart[NBUCK] = N_EDGES;
    }
    gsync(bar, 1);

    // ---------------- P3: binned scatter of packed edges ----------------
    {
        int* ha    = smem;
        int* gbase = smem + NBUCK;
        int* lcur  = smem + 2 * NBUCK;
        for (int ch = blockIdx.x; ch < NCHUNK; ch += NB) {
            int e0 = ch * CHUNK;
            int e1 = e0 + CHUNK;
            if (e1 > N_EDGES) e1 = N_EDGES;
            for (int i = tid; i < NBUCK; i += BT) ha[i] = 0;
            __syncthreads();
            int dloc[EPT];
#pragma unroll
            for (int i = 0; i < EPT; i++) {
                int e = e0 + tid + i * BT;
                dloc[i] = (e < e1) ? dst[e] : -1;
                if (dloc[i] >= 0) atomicAdd(&ha[dloc[i] >> SHIFT], 1);
            }
            __syncthreads();
            for (int s = tid; s < NBUCK; s += BT) {
                int c = ha[s];
                lcur[s] = 0;
                gbase[s] = c ? atomicAdd(&bcur[s], c) : 0;
            }
            __syncthreads();
#pragma unroll
            for (int i = 0; i < EPT; i++) {
                int d = dloc[i];
                if (d >= 0) {
                    int e = e0 + tid + i * BT;
                    int bk = d >> SHIFT;
                    int idx = atomicAdd(&lcur[bk], 1);
                    binned[gbase[bk] + idx] =
                        ((unsigned int)(d & (BWIDTH - 1)) << 17) | (unsigned int)src[e];
                }
            }
            __syncthreads();
        }
    }
    gsync(bar, 2);

    // ---------------- P4: per-bucket CSR ----------------
    {
        int* cnt = smem;
        int* s   = smem + BWIDTH;
        int* cur = smem + 2 * BWIDTH;
        for (int b = blockIdx.x; b < NBUCK; b += NB) {
            int base = b << SHIFT;
            int e0 = bstart[b], e1 = bstart[b + 1];
            if (tid < BWIDTH) cnt[tid] = 0;
            __syncthreads();
            for (int e = e0 + tid; e < e1; e += BT)
                atomicAdd(&cnt[binned[e] >> 17], 1);
            __syncthreads();
            int v = 0;
            if (tid < BWIDTH) { v = cnt[tid]; s[tid] = v; }
            __syncthreads();
            for (int off = 1; off < BWIDTH; off <<= 1) {
                int t = 0;
                if (tid < BWIDTH && tid >= off) t = s[tid - off];
                __syncthreads();
                if (tid < BWIDTH) s[tid] += t;
                __syncthreads();
            }
            if (tid < BWIDTH) {
                int ex = s[tid] - v;
                cur[tid] = ex;
                int node = base + tid;
                if (node < N_NODES) {
                    rp[node] = e0 + ex;
                    dinv[node] = rsqrtf((float)(v + 1));
                }
            }
            if (b == 0 && tid == 0) rp[N_NODES] = N_EDGES;
            __syncthreads();
            for (int e = e0 + tid; e < e1; e += BT) {
                unsigned int w = binned[e];
                int ln = (int)(w >> 17);
                int p = atomicAdd(&cur[ln], 1);
                col[e0 + p] = (int)(w & 0x1FFFFu);
            }
            __syncthreads();
        }
    }
    gsync(bar, 3);

    // ---------------- P5: h0s = dinv * (x @ W1) ----------------
    {
        float* xT = (float*)smem;   // 2 x 64 x 36 floats = 18432 B
        int rf0 = tid >> 3, kq = tid & 7;
        int rf1 = rf0 + 32;
        int r  = tid & 63;
        int cg = __builtin_amdgcn_readfirstlane(tid >> 6);
        const float4* W4 = (const float4*)W1;
        float4 zero4 = make_float4(0.f, 0.f, 0.f, 0.f);

        for (int t = blockIdx.x; t < XW_TILES; t += NB) {
            int rowBase = t * XW_ROWS;
            bool v0 = (rowBase + rf0) < N_NODES;
            bool v1 = (rowBase + rf1) < N_NODES;
            const float4* xrow0 = (const float4*)(x + (size_t)(rowBase + rf0) * F_IN);
            const float4* xrow1 = (const float4*)(x + (size_t)(rowBase + rf1) * F_IN);
            float4 acc = zero4;
            float4 ld0 = v0 ? xrow0[kq] : zero4;
            float4 ld1 = v1 ? xrow1[kq] : zero4;

            for (int kt = 0; kt < XW_NT; kt++) {
                float* xb = xT + (kt & 1) * (XW_ROWS * XW_S);
                *(float4*)&xb[rf0 * XW_S + kq * 4] = ld0;
                *(float4*)&xb[rf1 * XW_S + kq * 4] = ld1;
                if (kt + 1 < XW_NT) {
                    ld0 = v0 ? xrow0[(kt + 1) * 8 + kq] : zero4;
                    ld1 = v1 ? xrow1[(kt + 1) * 8 + kq] : zero4;
                }
                __syncthreads();
                const float* xr = &xb[r * XW_S];
#pragma unroll
                for (int k8 = 0; k8 < 8; k8++) {
                    float4 xv = *(const float4*)&xr[k8 * 4];
                    float4 w0 = W4[(kt * XW_KT + k8 * 4 + 0) * 4 + cg];
                    acc.x += xv.x * w0.x; acc.y += xv.x * w0.y;
                    acc.z += xv.x * w0.z; acc.w += xv.x * w0.w;
                    float4 w1 = W4[(kt * XW_KT + k8 * 4 + 1) * 4 + cg];
                    acc.x += xv.y * w1.x; acc.y += xv.y * w1.y;
                    acc.z += xv.y * w1.z; acc.w += xv.y * w1.w;
                    float4 w2 = W4[(kt * XW_KT + k8 * 4 + 2) * 4 + cg];
                    acc.x += xv.z * w2.x; acc.y += xv.z * w2.y;
                    acc.z += xv.z * w2.z; acc.w += xv.z * w2.w;
                    float4 w3 = W4[(kt * XW_KT + k8 * 4 + 3) * 4 + cg];
                    acc.x += xv.w * w3.x; acc.y += xv.w * w3.y;
                    acc.z += xv.w * w3.z; acc.w += xv.w * w3.w;
                }
                __syncthreads();
            }
            int node = rowBase + r;
            if (node < N_NODES) {
                float dv = dinv[node];
                float4 o;
                o.x = dv * acc.x; o.y = dv * acc.y;
                o.z = dv * acc.z; o.w = dv * acc.w;
                ((float4*)h0s)[(size_t)node * 4 + cg] = o;
            }
        }
    }
    gsync(bar, 4);

    // ---------------- P6: aggregate 1 (wave per node, x4 unroll) ----------------
    {
        int wid = blockIdx.x * (BT / 64) + (tid >> 6);
        int lane = tid & 63;
        int c = lane & 15, eo = lane >> 4;
        for (int node = wid; node < N_NODES; node += NWAVES) {
            int e0 = rp[node], e1 = rp[node + 1];
            float acc = 0.f;
            int e = e0 + eo;
            for (; e + 12 < e1; e += 16) {
                int c0 = col[e];
                int c1 = col[e + 4];
                int c2 = col[e + 8];
                int c3 = col[e + 12];
                float v0 = h0s[(size_t)c0 * HID + c];
                float v1 = h0s[(size_t)c1 * HID + c];
                float v2 = h0s[(size_t)c2 * HID + c];
                float v3 = h0s[(size_t)c3 * HID + c];
                acc += v0;
                acc += v1;
                acc += v2;
                acc += v3;
            }
            for (; e + 4 < e1; e += 8) {
                int c0 = col[e];
                int c1 = col[e + 4];
                float v0 = h0s[(size_t)c0 * HID + c];
                float v1 = h0s[(size_t)c1 * HID + c];
                acc += v0;
                acc += v1;
            }
            if (e < e1) acc += h0s[(size_t)col[e] * HID + c];
            acc += __shfl_xor(acc, 16);
            acc += __shfl_xor(acc, 32);
            float o = dinv[node] * (acc + h0s[(size_t)node * HID + c]) + b1[c];
            if (eo == 0) h1[(size_t)node * HID + c] = fmaxf(o, 0.f);
        }
    }
    gsync(bar, 5);

    // ---------------- P7: 10 fused hops + zs = dinv * (h @ W2) ----------------
    {
        for (int node = blockIdx.x * BT + tid; node < N_NODES; node += NB * BT) {
            float h[HID];
            const float4* h4 = (const float4*)(h1 + (size_t)node * HID);
#pragma unroll
            for (int q = 0; q < HID / 4; q++) {
                float4 v = h4[q];
                h[q * 4 + 0] = v.x; h[q * 4 + 1] = v.y;
                h[q * 4 + 2] = v.z; h[q * 4 + 3] = v.w;
            }
            for (int it = 0; it < K_HOPS; it++) {
                float tm[HID];
#pragma unroll
                for (int cc = 0; cc < HID; cc++) tm[cc] = bl[cc];
#pragma unroll
                for (int k = 0; k < HID; k++) {
                    float hk = h[k];
#pragma unroll
                    for (int cc = 0; cc < HID; cc++) tm[cc] += hk * Wl[k * HID + cc];
                }
#pragma unroll
                for (int cc = 0; cc < HID; cc++)
                    h[cc] = ALPHA * fmaxf(tm[cc], 0.f) + (1.f - ALPHA) * h[cc];
            }
            float dv = dinv[node];
            float zz[8];
#pragma unroll
            for (int cc = 0; cc < 8; cc++) zz[cc] = 0.f;
#pragma unroll
            for (int k = 0; k < HID; k++) {
                float hk = h[k];
#pragma unroll
                for (int cc = 0; cc < NCLS; cc++) zz[cc] += hk * W2[k * NCLS + cc];
            }
            float4* z4 = (float4*)(zs + (size_t)node * 8);
            float4 v0, v1;
            v0.x = dv * zz[0]; v0.y = dv * zz[1]; v0.z = dv * zz[2]; v0.w = dv * zz[3];
            v1.x = dv * zz[4]; v1.y = dv * zz[5]; v1.z = dv * zz[6]; v1.w = 0.f;
            z4[0] = v0; z4[1] = v1;
        }
    }
    gsync(bar, 6);

    // ---------------- P8: aggregate 2 + log_softmax ----------------
    {
        int wid = blockIdx.x * (BT / 64) + (tid >> 6);
        int lane = tid & 63;
        int c = lane & 7, eo = lane >> 3;
        for (int node = wid; node < N_NODES; node += NWAVES) {
            int e0 = rp[node], e1 = rp[node + 1];
            float acc = 0.f;
            int e = e0 + eo;
            for (; e + 24 < e1; e += 32) {
                int c0 = col[e];
                int c1 = col[e + 8];
                int c2 = col[e + 16];
                int c3 = col[e + 24];
                float v0 = zs[(size_t)c0 * 8 + c];
                float v1 = zs[(size_t)c1 * 8 + c];
                float v2 = zs[(size_t)c2 * 8 + c];
                float v3 = zs[(size_t)c3 * 8 + c];
                acc += v0;
                acc += v1;
                acc += v2;
                acc += v3;
            }
            for (; e + 8 < e1; e += 16) {
                int c0 = col[e];
                int c1 = col[e + 8];
                float v0 = zs[(size_t)c0 * 8 + c];
                float v1 = zs[(size_t)c1 * 8 + c];
                acc += v0;
                acc += v1;
            }
            if (e < e1) acc += zs[(size_t)col[e] * 8 + c];
            acc += __shfl_xor(acc, 8);
            acc += __shfl_xor(acc, 16);
            acc += __shfl_xor(acc, 32);
            float o = dinv[node] * (acc + zs[(size_t)node * 8 + c])
                      + ((c < NCLS) ? b2[c] : 0.f);
            float val = (c < NCLS) ? o : -INFINITY;
            float m = val;
            m = fmaxf(m, __shfl_xor(m, 1));
            m = fmaxf(m, __shfl_xor(m, 2));
            m = fmaxf(m, __shfl_xor(m, 4));
            float ex = (c < NCLS) ? expf(o - m) : 0.f;
            float ss = ex;
            ss += __shfl_xor(ss, 1);
            ss += __shfl_xor(ss, 2);
            ss += __shfl_xor(ss, 4);
            if (eo == 0 && c < NCLS) out[(size_t)node * NCLS + c] = o - m - logf(ss);
        }
    }
}

extern "C" void kernel_launch(void* const* d_in, const int* in_sizes, int n_in,
                              void* d_out, int out_size, void* d_ws, size_t ws_size,
                              hipStream_t stream) {
    const float* x  = (const float*)d_in[0];
    const int*   ei = (const int*)d_in[1];
    const float* W1 = (const float*)d_in[2];
    const float* b1 = (const float*)d_in[3];
    const float* Wl = (const float*)d_in[4];
    const float* bl = (const float*)d_in[5];
    const float* W2 = (const float*)d_in[6];
    const float* b2 = (const float*)d_in[7];
    float* out = (float*)d_out;

    int*   wsI = (int*)d_ws;
    float* wsF = (float*)d_ws;
    int*          bar    = wsI + OFF_BAR;
    int*          bcnt   = wsI + OFF_BCNT;
    int*          bstart = wsI + OFF_BSTART;
    int*          bcur   = wsI + OFF_BCUR;
    int*          rp     = wsI + OFF_RP;
    float*        dinv   = wsF + OFF_DINV;
    int*          col    = wsI + OFF_COL;
    unsigned int* binned = (unsigned int*)(wsI + OFF_BINNED);
    float*        h0s    = wsF + OFF_H0;
    float*        h1     = wsF + OFF_H1;
    float*        zs     = wsF + OFF_Z;

    const int* src = ei;
    const int* dst = ei + N_EDGES;

    // zero barrier counters + bucket counts in one memset
    hipMemsetAsync(wsI, 0, (OFF_BCNT + NBUCK) * sizeof(int), stream);

    k_fused<<<NB, BT, 0, stream>>>(x, src, dst, W1, b1, Wl, bl, W2, b2,
                                   bar, bcnt, bstart, bcur, rp, dinv,
                                   col, binned, h0s, h1, zs, out);
}

// Round 7
// 1643.627 us; speedup vs baseline: 1.0491x; 1.0491x over previous
//
#include <hip/hip_runtime.h>
#include <math.h>

#define N_NODES 100000
#define N_EDGES 3200000
#define F_IN    512
#define HID     16
#define NCLS    7
#define ALPHA   0.1f
#define K_HOPS  10

// bucketing: 128 nodes per bucket
#define SHIFT   7
#define BWIDTH  128
#define NBUCK   ((N_NODES + BWIDTH - 1) / BWIDTH)   // 782
#define CHUNK   4096
#define BIN_T   512
#define EPT     (CHUNK / BIN_T)                      // 8 edges per thread
#define A3_BLOCKS ((N_EDGES + CHUNK - 1) / CHUNK)   // 782

// ---- DIAGNOSTIC REPEATS (this round only): idempotent kernels re-run REP x
// inside one dispatch so their dur exceeds the ~120us harness fills and shows
// in top-5.  t_kernel = dur_row / REP.  Strip next round.
#define REP_CSR  6
#define REP_XW   5
#define REP_A1   5
#define REP_HOPS 12
#define REP_A2   8

// ---- workspace layout (4-byte element offsets); no aliasing ----
#define OFF_BCNT    0u          // int[782]
#define OFF_BSTART  1024u       // int[783]
#define OFF_BCUR    2048u       // int[782]
#define OFF_RP      3072u       // int[100001]
#define OFF_DINV    103424u     // float[100000]
#define OFF_COL     203776u     // int[3200000]
#define OFF_BINNED  3403776u    // uint[3200000]
#define OFF_H0      6603776u    // float[100000*16]
#define OFF_H1      8203776u    // float[100000*16]
#define OFF_Z       9803776u    // float[100000*8]

// ---------------- A1: global bucket histogram ----------------
__global__ void k_bhist(const int* __restrict__ dst, int* __restrict__ bcnt) {
    __shared__ int h[NBUCK];
    int tid = threadIdx.x;
    for (int i = tid; i < NBUCK; i += 256) h[i] = 0;
    __syncthreads();
    for (int e = blockIdx.x * 256 + tid; e < N_EDGES; e += gridDim.x * 256)
        atomicAdd(&h[dst[e] >> SHIFT], 1);
    __syncthreads();
    for (int i = tid; i < NBUCK; i += 256) {
        int v = h[i];
        if (v) atomicAdd(&bcnt[i], v);
    }
}

// ---------------- A2: scan bucket counts ----------------
__global__ void k_bscan(const int* __restrict__ bcnt, int* __restrict__ bstart,
                        int* __restrict__ bcur) {
    __shared__ int s[1024];
    int tid = threadIdx.x;
    int v = (tid < NBUCK) ? bcnt[tid] : 0;
    s[tid] = v;
    __syncthreads();
    for (int off = 1; off < 1024; off <<= 1) {
        int t = (tid >= off) ? s[tid - off] : 0;
        __syncthreads();
        s[tid] += t;
        __syncthreads();
    }
    if (tid < NBUCK) {
        int ex = s[tid] - v;     // exclusive
        bstart[tid] = ex;
        bcur[tid] = ex;
    }
    if (tid == 0) bstart[NBUCK] = N_EDGES;
}

// ---------------- A3: binned scatter of packed edges ----------------
__global__ void __launch_bounds__(BIN_T)
k_bin(const int* __restrict__ src, const int* __restrict__ dst,
      int* __restrict__ bcur, unsigned int* __restrict__ binned) {
    __shared__ int ha[NBUCK];
    __shared__ int gbase[NBUCK];
    __shared__ int lcur[NBUCK];
    int tid = threadIdx.x;
    int e0 = blockIdx.x * CHUNK;
    int e1 = e0 + CHUNK;
    if (e1 > N_EDGES) e1 = N_EDGES;
    for (int i = tid; i < NBUCK; i += BIN_T) ha[i] = 0;
    __syncthreads();
    int dloc[EPT];
#pragma unroll
    for (int i = 0; i < EPT; i++) {
        int e = e0 + tid + i * BIN_T;
        dloc[i] = (e < e1) ? dst[e] : -1;
        if (dloc[i] >= 0) atomicAdd(&ha[dloc[i] >> SHIFT], 1);
    }
    __syncthreads();
    for (int s = tid; s < NBUCK; s += BIN_T) {
        int c = ha[s];
        lcur[s] = 0;
        gbase[s] = c ? atomicAdd(&bcur[s], c) : 0;
    }
    __syncthreads();
#pragma unroll
    for (int i = 0; i < EPT; i++) {
        int d = dloc[i];
        if (d >= 0) {
            int e = e0 + tid + i * BIN_T;
            int bk = d >> SHIFT;
            int idx = atomicAdd(&lcur[bk], 1);
            binned[gbase[bk] + idx] =
                ((unsigned int)(d & (BWIDTH - 1)) << 17) | (unsigned int)src[e];
        }
    }
}

// ---------------- B: per-bucket CSR (count, scan, rp/dinv, col scatter) ----------------
__global__ void __launch_bounds__(512)
k_csr(const unsigned int* __restrict__ binned, const int* __restrict__ bstart,
      int* __restrict__ rp, float* __restrict__ dinv, int* __restrict__ col) {
    __shared__ int cnt[BWIDTH];
    __shared__ int s[BWIDTH];
    __shared__ int cur[BWIDTH];
    int tid = threadIdx.x;
    int b = blockIdx.x;
    int base = b << SHIFT;
    int e0 = bstart[b], e1 = bstart[b + 1];
    for (int rep = 0; rep < REP_CSR; rep++) {
        asm volatile("" ::: "memory");
        if (tid < BWIDTH) cnt[tid] = 0;
        __syncthreads();
        for (int e = e0 + tid; e < e1; e += 512)
            atomicAdd(&cnt[binned[e] >> 17], 1);
        __syncthreads();
        int v = 0;
        if (tid < BWIDTH) { v = cnt[tid]; s[tid] = v; }
        __syncthreads();
        for (int off = 1; off < BWIDTH; off <<= 1) {
            int t = 0;
            if (tid < BWIDTH && tid >= off) t = s[tid - off];
            __syncthreads();
            if (tid < BWIDTH) s[tid] += t;
            __syncthreads();
        }
        if (tid < BWIDTH) {
            int ex = s[tid] - v;
            cur[tid] = ex;
            int node = base + tid;
            if (node < N_NODES) {
                rp[node] = e0 + ex;
                dinv[node] = rsqrtf((float)(v + 1));
            }
        }
        if (b == 0 && tid == 0) rp[N_NODES] = N_EDGES;
        __syncthreads();
        for (int e = e0 + tid; e < e1; e += 512) {
            unsigned int w = binned[e];
            int ln = (int)(w >> 17);
            int p = atomicAdd(&cur[ln], 1);
            col[e0 + p] = (int)(w & 0x1FFFFu);
        }
        __syncthreads();
    }
}

// ---------------- h0s = dinv * (x @ W1): LDS-tiled GEMM, b128 reads ----------------
// x tile stored row-major [64][37]: stride-37 floats -> <=2-way banks on both
// the float4 writes and reads (stride 36 was 8-way: (36r+4k)%32 = 4(r+k)%32).
#define XW_ROWS 64
#define XW_KT   32
#define XW_S    37
#define XW_NT   (F_IN / XW_KT)   // 16 tiles
__global__ void k_xw1(const float* __restrict__ x, const float* __restrict__ W,
                      const float* __restrict__ dinv, float* __restrict__ h0s) {
    __shared__ float xT[2][XW_ROWS * XW_S];
    int tid = threadIdx.x;
    int rowBase = blockIdx.x * XW_ROWS;

    int rf0 = tid >> 3, kq = tid & 7;    // row 0..31, float4-col 0..7
    int rf1 = rf0 + 32;
    bool v0 = (rowBase + rf0) < N_NODES;
    bool v1 = (rowBase + rf1) < N_NODES;
    const float4* xrow0 = (const float4*)(x + (size_t)(rowBase + rf0) * F_IN);
    const float4* xrow1 = (const float4*)(x + (size_t)(rowBase + rf1) * F_IN);

    int r  = tid & 63;
    int cg = __builtin_amdgcn_readfirstlane(tid >> 6);   // wave-uniform -> s_load W
    const float4* W4 = (const float4*)W;
    float4 zero4 = make_float4(0.f, 0.f, 0.f, 0.f);

    for (int rep = 0; rep < REP_XW; rep++) {
        asm volatile("" ::: "memory");
        float4 acc = zero4;
        float4 ld0 = v0 ? xrow0[kq] : zero4;
        float4 ld1 = v1 ? xrow1[kq] : zero4;

        for (int kt = 0; kt < XW_NT; kt++) {
            float* xb = xT[kt & 1];
            *(float4*)&xb[rf0 * XW_S + kq * 4] = ld0;
            *(float4*)&xb[rf1 * XW_S + kq * 4] = ld1;
            if (kt + 1 < XW_NT) {
                ld0 = v0 ? xrow0[(kt + 1) * 8 + kq] : zero4;
                ld1 = v1 ? xrow1[(kt + 1) * 8 + kq] : zero4;
            }
            __syncthreads();
            const float* xr = &xb[r * XW_S];
#pragma unroll
            for (int k8 = 0; k8 < 8; k8++) {
                float4 xv = *(const float4*)&xr[k8 * 4];
                float4 w0 = W4[(kt * XW_KT + k8 * 4 + 0) * 4 + cg];
                acc.x += xv.x * w0.x; acc.y += xv.x * w0.y;
                acc.z += xv.x * w0.z; acc.w += xv.x * w0.w;
                float4 w1 = W4[(kt * XW_KT + k8 * 4 + 1) * 4 + cg];
                acc.x += xv.y * w1.x; acc.y += xv.y * w1.y;
                acc.z += xv.y * w1.z; acc.w += xv.y * w1.w;
                float4 w2 = W4[(kt * XW_KT + k8 * 4 + 2) * 4 + cg];
                acc.x += xv.z * w2.x; acc.y += xv.z * w2.y;
                acc.z += xv.z * w2.z; acc.w += xv.z * w2.w;
                float4 w3 = W4[(kt * XW_KT + k8 * 4 + 3) * 4 + cg];
                acc.x += xv.w * w3.x; acc.y += xv.w * w3.y;
                acc.z += xv.w * w3.z; acc.w += xv.w * w3.w;
            }
            __syncthreads();
        }
        int node = rowBase + r;
        if (node < N_NODES) {
            float dv = dinv[node];
            float4 o;
            o.x = dv * acc.x; o.y = dv * acc.y; o.z = dv * acc.z; o.w = dv * acc.w;
            ((float4*)h0s)[(size_t)node * 4 + cg] = o;
        }
    }
}

// ---------------- aggregate 1: one wave per node, x4 unroll ----------------
__global__ void k_agg1(const float* __restrict__ h0s, const int* __restrict__ rp,
                       const int* __restrict__ col, const float* __restrict__ dinv,
                       const float* __restrict__ b1, float* __restrict__ h1) {
    int node = (blockIdx.x * blockDim.x + threadIdx.x) >> 6;
    int lane = threadIdx.x & 63;
    int c = lane & 15, eo = lane >> 4;
    for (int rep = 0; rep < REP_A1; rep++) {
        asm volatile("" ::: "memory");
        if (node < N_NODES) {
            int e0 = rp[node], e1 = rp[node + 1];
            float acc = 0.f;
            int e = e0 + eo;
            for (; e + 12 < e1; e += 16) {
                int c0 = col[e];
                int c1 = col[e + 4];
                int c2 = col[e + 8];
                int c3 = col[e + 12];
                float v0 = h0s[(size_t)c0 * HID + c];
                float v1 = h0s[(size_t)c1 * HID + c];
                float v2 = h0s[(size_t)c2 * HID + c];
                float v3 = h0s[(size_t)c3 * HID + c];
                acc += v0;
                acc += v1;
                acc += v2;
                acc += v3;
            }
            for (; e + 4 < e1; e += 8) {
                int c0 = col[e];
                int c1 = col[e + 4];
                float v0 = h0s[(size_t)c0 * HID + c];
                float v1 = h0s[(size_t)c1 * HID + c];
                acc += v0;
                acc += v1;
            }
            if (e < e1) acc += h0s[(size_t)col[e] * HID + c];
            acc += __shfl_xor(acc, 16);
            acc += __shfl_xor(acc, 32);
            float o = dinv[node] * (acc + h0s[(size_t)node * HID + c]) + b1[c];
            if (eo == 0) h1[(size_t)node * HID + c] = fmaxf(o, 0.f);
        }
    }
}

// ---------------- 10 fused hops + zs = dinv * (h @ W2) ----------------
__global__ void k_hops(const float* __restrict__ h1, const float* __restrict__ Wl,
                       const float* __restrict__ bl, const float* __restrict__ W2,
                       const float* __restrict__ dinv, float* __restrict__ zs) {
    int node = blockIdx.x * blockDim.x + threadIdx.x;
    for (int rep = 0; rep < REP_HOPS; rep++) {
        asm volatile("" ::: "memory");
        if (node < N_NODES) {
            float h[HID];
            const float4* h4 = (const float4*)(h1 + (size_t)node * HID);
#pragma unroll
            for (int q = 0; q < HID / 4; q++) {
                float4 v = h4[q];
                h[q * 4 + 0] = v.x; h[q * 4 + 1] = v.y;
                h[q * 4 + 2] = v.z; h[q * 4 + 3] = v.w;
            }
            for (int it = 0; it < K_HOPS; it++) {
                float tm[HID];
#pragma unroll
                for (int cc = 0; cc < HID; cc++) tm[cc] = bl[cc];
#pragma unroll
                for (int k = 0; k < HID; k++) {
                    float hk = h[k];
#pragma unroll
                    for (int cc = 0; cc < HID; cc++) tm[cc] += hk * Wl[k * HID + cc];
                }
#pragma unroll
                for (int cc = 0; cc < HID; cc++)
                    h[cc] = ALPHA * fmaxf(tm[cc], 0.f) + (1.f - ALPHA) * h[cc];
            }
            float dv = dinv[node];
            float zz[8];
#pragma unroll
            for (int cc = 0; cc < 8; cc++) zz[cc] = 0.f;
#pragma unroll
            for (int k = 0; k < HID; k++) {
                float hk = h[k];
#pragma unroll
                for (int cc = 0; cc < NCLS; cc++) zz[cc] += hk * W2[k * NCLS + cc];
            }
            float4* z4 = (float4*)(zs + (size_t)node * 8);
            float4 v0, v1;
            v0.x = dv * zz[0]; v0.y = dv * zz[1]; v0.z = dv * zz[2]; v0.w = dv * zz[3];
            v1.x = dv * zz[4]; v1.y = dv * zz[5]; v1.z = dv * zz[6]; v1.w = 0.f;
            z4[0] = v0; z4[1] = v1;
        }
    }
}

// ---------------- aggregate 2 + log_softmax: one wave per node, x4 unroll ----------------
__global__ void k_agg2(const float* __restrict__ zs, const int* __restrict__ rp,
                       const int* __restrict__ col, const float* __restrict__ dinv,
                       const float* __restrict__ b2, float* __restrict__ out) {
    int node = (blockIdx.x * blockDim.x + threadIdx.x) >> 6;
    int lane = threadIdx.x & 63;
    int c = lane & 7, eo = lane >> 3;
    for (int rep = 0; rep < REP_A2; rep++) {
        asm volatile("" ::: "memory");
        if (node < N_NODES) {
            int e0 = rp[node], e1 = rp[node + 1];
            float acc = 0.f;
            int e = e0 + eo;
            for (; e + 24 < e1; e += 32) {
                int c0 = col[e];
                int c1 = col[e + 8];
                int c2 = col[e + 16];
                int c3 = col[e + 24];
                float v0 = zs[(size_t)c0 * 8 + c];
                float v1 = zs[(size_t)c1 * 8 + c];
                float v2 = zs[(size_t)c2 * 8 + c];
                float v3 = zs[(size_t)c3 * 8 + c];
                acc += v0;
                acc += v1;
                acc += v2;
                acc += v3;
            }
            for (; e + 8 < e1; e += 16) {
                int c0 = col[e];
                int c1 = col[e + 8];
                float v0 = zs[(size_t)c0 * 8 + c];
                float v1 = zs[(size_t)c1 * 8 + c];
                acc += v0;
                acc += v1;
            }
            if (e < e1) acc += zs[(size_t)col[e] * 8 + c];
            acc += __shfl_xor(acc, 8);
            acc += __shfl_xor(acc, 16);
            acc += __shfl_xor(acc, 32);
            float o = dinv[node] * (acc + zs[(size_t)node * 8 + c])
                      + ((c < NCLS) ? b2[c] : 0.f);
            float val = (c < NCLS) ? o : -INFINITY;
            float m = val;
            m = fmaxf(m, __shfl_xor(m, 1));
            m = fmaxf(m, __shfl_xor(m, 2));
            m = fmaxf(m, __shfl_xor(m, 4));
            float ex = (c < NCLS) ? expf(o - m) : 0.f;
            float ss = ex;
            ss += __shfl_xor(ss, 1);
            ss += __shfl_xor(ss, 2);
            ss += __shfl_xor(ss, 4);
            if (eo == 0 && c < NCLS) out[(size_t)node * NCLS + c] = o - m - logf(ss);
        }
    }
}

extern "C" void kernel_launch(void* const* d_in, const int* in_sizes, int n_in,
                              void* d_out, int out_size, void* d_ws, size_t ws_size,
                              hipStream_t stream) {
    const float* x  = (const float*)d_in[0];
    const int*   ei = (const int*)d_in[1];
    const float* W1 = (const float*)d_in[2];
    const float* b1 = (const float*)d_in[3];
    const float* Wl = (const float*)d_in[4];
    const float* bl = (const float*)d_in[5];
    const float* W2 = (const float*)d_in[6];
    const float* b2 = (const float*)d_in[7];
    float* out = (float*)d_out;

    int*   wsI = (int*)d_ws;
    float* wsF = (float*)d_ws;
    int*          bcnt   = wsI + OFF_BCNT;
    int*          bstart = wsI + OFF_BSTART;
    int*          bcur   = wsI + OFF_BCUR;
    int*          rp     = wsI + OFF_RP;
    float*        dinv   = wsF + OFF_DINV;
    int*          col    = wsI + OFF_COL;
    unsigned int* binned = (unsigned int*)(wsI + OFF_BINNED);
    float*        h0s    = wsF + OFF_H0;
    float*        h1     = wsF + OFF_H1;
    float*        zs     = wsF + OFF_Z;

    const int* src = ei;
    const int* dst = ei + N_EDGES;

    hipMemsetAsync(bcnt, 0, NBUCK * sizeof(int), stream);

    k_bhist<<<1024, 256, 0, stream>>>(dst, bcnt);
    k_bscan<<<1, 1024, 0, stream>>>(bcnt, bstart, bcur);
    k_bin<<<A3_BLOCKS, BIN_T, 0, stream>>>(src, dst, bcur, binned);
    k_csr<<<NBUCK, 512, 0, stream>>>(binned, bstart, rp, dinv, col);
    k_xw1<<<(N_NODES + XW_ROWS - 1) / XW_ROWS, 256, 0, stream>>>(x, W1, dinv, h0s);
    k_agg1<<<(N_NODES * 64 + 255) / 256, 256, 0, stream>>>(h0s, rp, col, dinv, b1, h1);
    k_hops<<<(N_NODES + 255) / 256, 256, 0, stream>>>(h1, Wl, bl, W2, dinv, zs);
    k_agg2<<<(N_NODES * 64 + 255) / 256, 256, 0, stream>>>(zs, rp, col, dinv, b2, out);
}

// Round 8
// 558.080 us; speedup vs baseline: 3.0896x; 2.9451x over previous
//
#include <hip/hip_runtime.h>
#include <math.h>

#define N_NODES 100000
#define N_EDGES 3200000
#define F_IN    512
#define HID     16
#define NCLS    7
#define ALPHA   0.1f
#define K_HOPS  10

// bucketing: 128 nodes per bucket
#define SHIFT   7
#define BWIDTH  128
#define NBUCK   ((N_NODES + BWIDTH - 1) / BWIDTH)   // 782
#define CHUNK   4096
#define BIN_T   512
#define EPT     (CHUNK / BIN_T)                      // 8 edges per thread
#define A3_BLOCKS ((N_EDGES + CHUNK - 1) / CHUNK)   // 782

// ---- workspace layout (4-byte element offsets); no aliasing ----
#define OFF_BCNT    0u          // int[782]
#define OFF_BSTART  1024u       // int[783]
#define OFF_BCUR    2048u       // int[782]
#define OFF_RP      3072u       // int[100001]
#define OFF_DINV    103424u     // float[100000]
#define OFF_COL     203776u     // int[3200000]
#define OFF_BINNED  3403776u    // uint[3200000]
#define OFF_H0      6603776u    // float[100000*16]
#define OFF_H1      8203776u    // float[100000*16]
#define OFF_Z       9803776u    // float[100000*8]

// ---------------- A1: global bucket histogram ----------------
__global__ void k_bhist(const int* __restrict__ dst, int* __restrict__ bcnt) {
    __shared__ int h[NBUCK];
    int tid = threadIdx.x;
    for (int i = tid; i < NBUCK; i += 256) h[i] = 0;
    __syncthreads();
    for (int e = blockIdx.x * 256 + tid; e < N_EDGES; e += gridDim.x * 256)
        atomicAdd(&h[dst[e] >> SHIFT], 1);
    __syncthreads();
    for (int i = tid; i < NBUCK; i += 256) {
        int v = h[i];
        if (v) atomicAdd(&bcnt[i], v);
    }
}

// ---------------- A2: scan bucket counts ----------------
__global__ void k_bscan(const int* __restrict__ bcnt, int* __restrict__ bstart,
                        int* __restrict__ bcur) {
    __shared__ int s[1024];
    int tid = threadIdx.x;
    int v = (tid < NBUCK) ? bcnt[tid] : 0;
    s[tid] = v;
    __syncthreads();
    for (int off = 1; off < 1024; off <<= 1) {
        int t = (tid >= off) ? s[tid - off] : 0;
        __syncthreads();
        s[tid] += t;
        __syncthreads();
    }
    if (tid < NBUCK) {
        int ex = s[tid] - v;     // exclusive
        bstart[tid] = ex;
        bcur[tid] = ex;
    }
    if (tid == 0) bstart[NBUCK] = N_EDGES;
}

// ---------------- A3: binned scatter of packed edges ----------------
__global__ void __launch_bounds__(BIN_T)
k_bin(const int* __restrict__ src, const int* __restrict__ dst,
      int* __restrict__ bcur, unsigned int* __restrict__ binned) {
    __shared__ int ha[NBUCK];
    __shared__ int gbase[NBUCK];
    __shared__ int lcur[NBUCK];
    int tid = threadIdx.x;
    int e0 = blockIdx.x * CHUNK;
    int e1 = e0 + CHUNK;
    if (e1 > N_EDGES) e1 = N_EDGES;
    for (int i = tid; i < NBUCK; i += BIN_T) ha[i] = 0;
    __syncthreads();
    int dloc[EPT];
#pragma unroll
    for (int i = 0; i < EPT; i++) {
        int e = e0 + tid + i * BIN_T;
        dloc[i] = (e < e1) ? dst[e] : -1;
        if (dloc[i] >= 0) atomicAdd(&ha[dloc[i] >> SHIFT], 1);
    }
    __syncthreads();
    for (int s = tid; s < NBUCK; s += BIN_T) {
        int c = ha[s];
        lcur[s] = 0;
        gbase[s] = c ? atomicAdd(&bcur[s], c) : 0;
    }
    __syncthreads();
#pragma unroll
    for (int i = 0; i < EPT; i++) {
        int d = dloc[i];
        if (d >= 0) {
            int e = e0 + tid + i * BIN_T;
            int bk = d >> SHIFT;
            int idx = atomicAdd(&lcur[bk], 1);
            binned[gbase[bk] + idx] =
                ((unsigned int)(d & (BWIDTH - 1)) << 17) | (unsigned int)src[e];
        }
    }
}

// ---------------- B: per-bucket CSR (count, scan, rp/dinv, col scatter) ----------------
__global__ void __launch_bounds__(512)
k_csr(const unsigned int* __restrict__ binned, const int* __restrict__ bstart,
      int* __restrict__ rp, float* __restrict__ dinv, int* __restrict__ col) {
    __shared__ int cnt[BWIDTH];
    __shared__ int s[BWIDTH];
    __shared__ int cur[BWIDTH];
    int tid = threadIdx.x;
    int b = blockIdx.x;
    int base = b << SHIFT;
    int e0 = bstart[b], e1 = bstart[b + 1];
    if (tid < BWIDTH) cnt[tid] = 0;
    __syncthreads();
    for (int e = e0 + tid; e < e1; e += 512)
        atomicAdd(&cnt[binned[e] >> 17], 1);
    __syncthreads();
    int v = 0;
    if (tid < BWIDTH) { v = cnt[tid]; s[tid] = v; }
    __syncthreads();
    for (int off = 1; off < BWIDTH; off <<= 1) {
        int t = 0;
        if (tid < BWIDTH && tid >= off) t = s[tid - off];
        __syncthreads();
        if (tid < BWIDTH) s[tid] += t;
        __syncthreads();
    }
    if (tid < BWIDTH) {
        int ex = s[tid] - v;
        cur[tid] = ex;
        int node = base + tid;
        if (node < N_NODES) {
            rp[node] = e0 + ex;
            dinv[node] = rsqrtf((float)(v + 1));
        }
    }
    if (b == 0 && tid == 0) rp[N_NODES] = N_EDGES;
    __syncthreads();
    for (int e = e0 + tid; e < e1; e += 512) {
        unsigned int w = binned[e];
        int ln = (int)(w >> 17);
        int p = atomicAdd(&cur[ln], 1);
        col[e0 + p] = (int)(w & 0x1FFFFu);
    }
}

// ---------------- h0s = dinv * (x @ W1): wave-per-node, zero barriers ----------------
// Lane l holds x[node][8l..8l+8) in regs (2 coalesced float4 loads) and
// W1 rows [8l..8l+8) x 16 cols in 128 VGPRs (loaded once).  128 static FMAs,
// then a reduce-scatter butterfly (xor 32/16/8/4 halving values, xor 1/2
// finishing) so lane 4*c holds out[c] -- no runtime-indexed arrays.
#define XWN_BLOCKS 512
#define XWN_WAVES  (XWN_BLOCKS * 4)   // 2048

__device__ __forceinline__ float4 shfl4_xor(float4 v, int m) {
    float4 r;
    r.x = __shfl_xor(v.x, m);
    r.y = __shfl_xor(v.y, m);
    r.z = __shfl_xor(v.z, m);
    r.w = __shfl_xor(v.w, m);
    return r;
}
__device__ __forceinline__ float4 add4(float4 a, float4 b) {
    a.x += b.x; a.y += b.y; a.z += b.z; a.w += b.w;
    return a;
}

__global__ void __launch_bounds__(256)
k_xw1(const float* __restrict__ x, const float* __restrict__ W,
      const float* __restrict__ dinv, float* __restrict__ h0s) {
    int lane = threadIdx.x & 63;
    int wid = (blockIdx.x * 256 + threadIdx.x) >> 6;   // 0..2047

    // W rows 8*lane .. 8*lane+7, all 16 cols -> 32 float4 regs
    float4 w[32];
    const float4* W4 = (const float4*)W;
#pragma unroll
    for (int j = 0; j < 8; j++) {
#pragma unroll
        for (int q = 0; q < 4; q++)
            w[j * 4 + q] = W4[(8 * lane + j) * 4 + q];
    }

    int node = wid;
    const float4* xr0 = (const float4*)(x + (size_t)node * F_IN) + 2 * lane;
    float4 xc0 = xr0[0];
    float4 xc1 = xr0[1];

    for (; node < N_NODES; node += XWN_WAVES) {
        // prefetch next node's row
        int nn = node + XWN_WAVES;
        float4 xn0, xn1;
        if (nn < N_NODES) {
            const float4* xr = (const float4*)(x + (size_t)nn * F_IN) + 2 * lane;
            xn0 = xr[0];
            xn1 = xr[1];
        }

        float xa0 = xc0.x, xa1 = xc0.y, xa2 = xc0.z, xa3 = xc0.w;
        float xa4 = xc1.x, xa5 = xc1.y, xa6 = xc1.z, xa7 = xc1.w;

        float4 pp0 = make_float4(0.f, 0.f, 0.f, 0.f);
        float4 pp1 = pp0, pp2 = pp0, pp3 = pp0;
#define XW_FMA(J, XA)                                            \
        pp0.x += XA * w[J*4+0].x; pp0.y += XA * w[J*4+0].y;      \
        pp0.z += XA * w[J*4+0].z; pp0.w += XA * w[J*4+0].w;      \
        pp1.x += XA * w[J*4+1].x; pp1.y += XA * w[J*4+1].y;      \
        pp1.z += XA * w[J*4+1].z; pp1.w += XA * w[J*4+1].w;      \
        pp2.x += XA * w[J*4+2].x; pp2.y += XA * w[J*4+2].y;      \
        pp2.z += XA * w[J*4+2].z; pp2.w += XA * w[J*4+2].w;      \
        pp3.x += XA * w[J*4+3].x; pp3.y += XA * w[J*4+3].y;      \
        pp3.z += XA * w[J*4+3].z; pp3.w += XA * w[J*4+3].w;
        XW_FMA(0, xa0) XW_FMA(1, xa1) XW_FMA(2, xa2) XW_FMA(3, xa3)
        XW_FMA(4, xa4) XW_FMA(5, xa5) XW_FMA(6, xa6) XW_FMA(7, xa7)
#undef XW_FMA

        // reduce-scatter butterfly: c bit3..bit0 = lane bit5..bit2
        int b5 = (lane >> 5) & 1;
        float4 k0 = b5 ? pp2 : pp0;
        float4 k1 = b5 ? pp3 : pp1;
        float4 s0 = b5 ? pp0 : pp2;
        float4 s1 = b5 ? pp1 : pp3;
        k0 = add4(k0, shfl4_xor(s0, 32));
        k1 = add4(k1, shfl4_xor(s1, 32));

        int b4 = (lane >> 4) & 1;
        float4 kk = b4 ? k1 : k0;
        float4 ss = b4 ? k0 : k1;
        kk = add4(kk, shfl4_xor(ss, 16));

        int b3 = (lane >> 3) & 1;
        float e0 = b3 ? kk.z : kk.x;
        float e1 = b3 ? kk.w : kk.y;
        float f0 = b3 ? kk.x : kk.z;
        float f1 = b3 ? kk.y : kk.w;
        e0 += __shfl_xor(f0, 8);
        e1 += __shfl_xor(f1, 8);

        int b2 = (lane >> 2) & 1;
        float v = b2 ? e1 : e0;
        float sv = b2 ? e0 : e1;
        v += __shfl_xor(sv, 4);

        v += __shfl_xor(v, 1);
        v += __shfl_xor(v, 2);

        if ((lane & 3) == 0) {
            float dv = dinv[node];
            h0s[(size_t)node * HID + (lane >> 2)] = dv * v;
        }

        xc0 = xn0;
        xc1 = xn1;
    }
}

// ---------------- aggregate 1: one wave per node, x4 unroll ----------------
__global__ void k_agg1(const float* __restrict__ h0s, const int* __restrict__ rp,
                       const int* __restrict__ col, const float* __restrict__ dinv,
                       const float* __restrict__ b1, float* __restrict__ h1) {
    int node = (blockIdx.x * blockDim.x + threadIdx.x) >> 6;
    if (node >= N_NODES) return;
    int lane = threadIdx.x & 63;
    int c = lane & 15, eo = lane >> 4;
    int e0 = rp[node], e1 = rp[node + 1];
    float acc = 0.f;
    int e = e0 + eo;
    for (; e + 12 < e1; e += 16) {
        int c0 = col[e];
        int c1 = col[e + 4];
        int c2 = col[e + 8];
        int c3 = col[e + 12];
        float v0 = h0s[(size_t)c0 * HID + c];
        float v1 = h0s[(size_t)c1 * HID + c];
        float v2 = h0s[(size_t)c2 * HID + c];
        float v3 = h0s[(size_t)c3 * HID + c];
        acc += v0;
        acc += v1;
        acc += v2;
        acc += v3;
    }
    for (; e + 4 < e1; e += 8) {
        int c0 = col[e];
        int c1 = col[e + 4];
        float v0 = h0s[(size_t)c0 * HID + c];
        float v1 = h0s[(size_t)c1 * HID + c];
        acc += v0;
        acc += v1;
    }
    if (e < e1) acc += h0s[(size_t)col[e] * HID + c];
    acc += __shfl_xor(acc, 16);
    acc += __shfl_xor(acc, 32);
    float o = dinv[node] * (acc + h0s[(size_t)node * HID + c]) + b1[c];
    if (eo == 0) h1[(size_t)node * HID + c] = fmaxf(o, 0.f);
}

// ---------------- 10 fused hops + zs = dinv * (h @ W2) ----------------
__global__ void k_hops(const float* __restrict__ h1, const float* __restrict__ Wl,
                       const float* __restrict__ bl, const float* __restrict__ W2,
                       const float* __restrict__ dinv, float* __restrict__ zs) {
    int node = blockIdx.x * blockDim.x + threadIdx.x;
    if (node >= N_NODES) return;
    float h[HID];
    const float4* h4 = (const float4*)(h1 + (size_t)node * HID);
#pragma unroll
    for (int q = 0; q < HID / 4; q++) {
        float4 v = h4[q];
        h[q * 4 + 0] = v.x; h[q * 4 + 1] = v.y;
        h[q * 4 + 2] = v.z; h[q * 4 + 3] = v.w;
    }
    for (int it = 0; it < K_HOPS; it++) {
        float tm[HID];
#pragma unroll
        for (int c = 0; c < HID; c++) tm[c] = bl[c];
#pragma unroll
        for (int k = 0; k < HID; k++) {
            float hk = h[k];
#pragma unroll
            for (int c = 0; c < HID; c++) tm[c] += hk * Wl[k * HID + c];
        }
#pragma unroll
        for (int c = 0; c < HID; c++)
            h[c] = ALPHA * fmaxf(tm[c], 0.f) + (1.f - ALPHA) * h[c];
    }
    float dv = dinv[node];
    float zz[8];
#pragma unroll
    for (int c = 0; c < 8; c++) zz[c] = 0.f;
#pragma unroll
    for (int k = 0; k < HID; k++) {
        float hk = h[k];
#pragma unroll
        for (int c = 0; c < NCLS; c++) zz[c] += hk * W2[k * NCLS + c];
    }
    float4* z4 = (float4*)(zs + (size_t)node * 8);
    float4 v0, v1;
    v0.x = dv * zz[0]; v0.y = dv * zz[1]; v0.z = dv * zz[2]; v0.w = dv * zz[3];
    v1.x = dv * zz[4]; v1.y = dv * zz[5]; v1.z = dv * zz[6]; v1.w = 0.f;
    z4[0] = v0; z4[1] = v1;
}

// ---------------- aggregate 2 + log_softmax: one wave per node, x4 unroll ----------------
__global__ void k_agg2(const float* __restrict__ zs, const int* __restrict__ rp,
                       const int* __restrict__ col, const float* __restrict__ dinv,
                       const float* __restrict__ b2, float* __restrict__ out) {
    int node = (blockIdx.x * blockDim.x + threadIdx.x) >> 6;
    if (node >= N_NODES) return;
    int lane = threadIdx.x & 63;
    int c = lane & 7, eo = lane >> 3;
    int e0 = rp[node], e1 = rp[node + 1];
    float acc = 0.f;
    int e = e0 + eo;
    for (; e + 24 < e1; e += 32) {
        int c0 = col[e];
        int c1 = col[e + 8];
        int c2 = col[e + 16];
        int c3 = col[e + 24];
        float v0 = zs[(size_t)c0 * 8 + c];
        float v1 = zs[(size_t)c1 * 8 + c];
        float v2 = zs[(size_t)c2 * 8 + c];
        float v3 = zs[(size_t)c3 * 8 + c];
        acc += v0;
        acc += v1;
        acc += v2;
        acc += v3;
    }
    for (; e + 8 < e1; e += 16) {
        int c0 = col[e];
        int c1 = col[e + 8];
        float v0 = zs[(size_t)c0 * 8 + c];
        float v1 = zs[(size_t)c1 * 8 + c];
        acc += v0;
        acc += v1;
    }
    if (e < e1) acc += zs[(size_t)col[e] * 8 + c];
    acc += __shfl_xor(acc, 8);
    acc += __shfl_xor(acc, 16);
    acc += __shfl_xor(acc, 32);
    float o = dinv[node] * (acc + zs[(size_t)node * 8 + c]) + ((c < NCLS) ? b2[c] : 0.f);
    float val = (c < NCLS) ? o : -INFINITY;
    float m = val;
    m = fmaxf(m, __shfl_xor(m, 1));
    m = fmaxf(m, __shfl_xor(m, 2));
    m = fmaxf(m, __shfl_xor(m, 4));
    float ex = (c < NCLS) ? expf(o - m) : 0.f;
    float ss = ex;
    ss += __shfl_xor(ss, 1);
    ss += __shfl_xor(ss, 2);
    ss += __shfl_xor(ss, 4);
    if (eo == 0 && c < NCLS) out[(size_t)node * NCLS + c] = o - m - logf(ss);
}

extern "C" void kernel_launch(void* const* d_in, const int* in_sizes, int n_in,
                              void* d_out, int out_size, void* d_ws, size_t ws_size,
                              hipStream_t stream) {
    const float* x  = (const float*)d_in[0];
    const int*   ei = (const int*)d_in[1];
    const float* W1 = (const float*)d_in[2];
    const float* b1 = (const float*)d_in[3];
    const float* Wl = (const float*)d_in[4];
    const float* bl = (const float*)d_in[5];
    const float* W2 = (const float*)d_in[6];
    const float* b2 = (const float*)d_in[7];
    float* out = (float*)d_out;

    int*   wsI = (int*)d_ws;
    float* wsF = (float*)d_ws;
    int*          bcnt   = wsI + OFF_BCNT;
    int*          bstart = wsI + OFF_BSTART;
    int*          bcur   = wsI + OFF_BCUR;
    int*          rp     = wsI + OFF_RP;
    float*        dinv   = wsF + OFF_DINV;
    int*          col    = wsI + OFF_COL;
    unsigned int* binned = (unsigned int*)(wsI + OFF_BINNED);
    float*        h0s    = wsF + OFF_H0;
    float*        h1     = wsF + OFF_H1;
    float*        zs     = wsF + OFF_Z;

    const int* src = ei;
    const int* dst = ei + N_EDGES;

    hipMemsetAsync(bcnt, 0, NBUCK * sizeof(int), stream);

    k_bhist<<<1024, 256, 0, stream>>>(dst, bcnt);
    k_bscan<<<1, 1024, 0, stream>>>(bcnt, bstart, bcur);
    k_bin<<<A3_BLOCKS, BIN_T, 0, stream>>>(src, dst, bcur, binned);
    k_csr<<<NBUCK, 512, 0, stream>>>(binned, bstart, rp, dinv, col);
    k_xw1<<<XWN_BLOCKS, 256, 0, stream>>>(x, W1, dinv, h0s);
    k_agg1<<<(N_NODES * 64 + 255) / 256, 256, 0, stream>>>(h0s, rp, col, dinv, b1, h1);
    k_hops<<<(N_NODES + 255) / 256, 256, 0, stream>>>(h1, Wl, bl, W2, dinv, zs);
    k_agg2<<<(N_NODES * 64 + 255) / 256, 256, 0, stream>>>(zs, rp, col, dinv, b2, out);
}